// Round 2
// baseline (161.708 us; speedup 1.0000x reference)
//
#include <hip/hip_runtime.h>

// KANN_4578435137547: quadratic Lagrange FEM basis + weight contraction.
// Single-pass writer: every output byte written exactly once (no memset, no RMW).
// Outputs (flat f32): t[32768], dt[32768], ddt[32768],
//   phi[32768][2049], dphi[32768][2049], ddphi[32768][2049].

#define KN_WIDTH    8
#define KN_NODES    2049
#define KN_SAMPLES  4096
#define KN_IK       (KN_SAMPLES * KN_WIDTH)            // 32768
#define KN_HEAD     (3 * KN_IK)                        // 98304
#define KN_PHI_LEN  ((size_t)KN_IK * KN_NODES)         // 67,141,632

__device__ __forceinline__ void kann_coord(float xv, int& nl, float& x_t) {
    float xs  = 2048.0f * xv;
    float fid = floorf(0.5f * xs);
    fid = fminf(fmaxf(fid, 0.0f), 1023.0f);
    nl  = 2 * (int)fid;                  // even, in [0, 2046]
    x_t = xs - ((float)nl + 1.0f);       // local coord in [-1, 1]
}

// Head: t/dt/ddt contractions, one thread per (i,k). 128 blocks.
__global__ __launch_bounds__(256)
void KANN_head(const float* __restrict__ x, const float* __restrict__ w,
               float* __restrict__ out) {
    int ik = blockIdx.x * 256 + threadIdx.x;
    if (ik >= KN_IK) return;
    int i = ik >> 3, k = ik & 7;
    int nl; float x_t; kann_coord(x[i], nl, x_t);
    float p0 = 0.5f * x_t * (x_t - 1.0f);
    float p1 = 1.0f - x_t * x_t;
    float p2 = 0.5f * x_t * (x_t + 1.0f);
    const float s = 2048.0f, s2 = 2048.0f * 2048.0f;
    const float* wk = w + k * KN_NODES + nl;
    float w0 = wk[0], w1 = wk[1], w2 = wk[2];
    out[ik]             = w0 * p0 + w1 * p1 + w2 * p2;
    out[KN_IK + ik]     = (w0 * (x_t - 0.5f) - 2.0f * w1 * x_t + w2 * (x_t + 0.5f)) * s;
    out[2 * KN_IK + ik] = (w0 - 2.0f * w1 + w2) * s2;
}

// Body: write one phi-family array (blockIdx.y selects which) in float4 units.
__global__ __launch_bounds__(256)
void KANN_body(const float* __restrict__ x, float* __restrict__ out) {
    const int y = blockIdx.y;                       // 0=phi, 1=dphi, 2=ddphi
    float* base = out + KN_HEAD + (size_t)y * KN_PHI_LEN;
    const unsigned nf4 = (unsigned)(KN_PHI_LEN / 4);   // 16,785,408
    const unsigned stride = gridDim.x * blockDim.x;

    for (unsigned f4 = blockIdx.x * blockDim.x + threadIdx.x; f4 < nf4; f4 += stride) {
        unsigned e0   = f4 * 4u;
        unsigned row  = e0 / KN_NODES;              // magic-mul divide
        unsigned col0 = e0 - row * KN_NODES;
        float vv[4] = {0.0f, 0.0f, 0.0f, 0.0f};

        if (col0 < KN_NODES - 3) {                  // window within one row
            int i = (int)(row >> 3);
            int nl; float x_t; kann_coord(x[i], nl, x_t);
            int d0 = (int)col0 - nl;                // element j nonzero iff d0+j in [0,2]
            if (d0 >= -3 && d0 <= 2) {
                float b0, b1, b2;
                if (y == 0)      { b0 = 0.5f * x_t * (x_t - 1.0f); b1 = 1.0f - x_t * x_t; b2 = 0.5f * x_t * (x_t + 1.0f); }
                else if (y == 1) { b0 = (x_t - 0.5f) * 2048.0f; b1 = -4096.0f * x_t; b2 = (x_t + 0.5f) * 2048.0f; }
                else             { b0 = 4194304.0f; b1 = -8388608.0f; b2 = 4194304.0f; }
#pragma unroll
                for (int j = 0; j < 4; ++j) {
                    int d = d0 + j;
                    vv[j] = (d == 0) ? b0 : ((d == 1) ? b1 : ((d == 2) ? b2 : 0.0f));
                }
            }
        } else {                                    // rare: window spans row boundary
#pragma unroll
            for (int j = 0; j < 4; ++j) {
                unsigned e = e0 + j;
                unsigned r = e / KN_NODES;
                unsigned c = e - r * KN_NODES;
                int i = (int)(r >> 3);
                int nl; float x_t; kann_coord(x[i], nl, x_t);
                int d = (int)c - nl;
                if (d >= 0 && d <= 2) {
                    float b;
                    if (y == 0)      b = (d == 0) ? 0.5f * x_t * (x_t - 1.0f) : ((d == 1) ? 1.0f - x_t * x_t : 0.5f * x_t * (x_t + 1.0f));
                    else if (y == 1) b = ((d == 0) ? (x_t - 0.5f) : ((d == 1) ? (-2.0f * x_t) : (x_t + 0.5f))) * 2048.0f;
                    else             b = (d == 1) ? -8388608.0f : 4194304.0f;
                    vv[j] = b;
                }
            }
        }
        float4 v = make_float4(vv[0], vv[1], vv[2], vv[3]);
        *reinterpret_cast<float4*>(base + (size_t)e0) = v;
    }
}

extern "C" void kernel_launch(void* const* d_in, const int* in_sizes, int n_in,
                              void* d_out, int out_size, void* d_ws, size_t ws_size,
                              hipStream_t stream) {
    const float* x = (const float*)d_in[0];
    const float* w = (const float*)d_in[1];
    float* out = (float*)d_out;

    KANN_head<<<dim3(KN_IK / 256), dim3(256), 0, stream>>>(x, w, out);
    KANN_body<<<dim3(1024, 3), dim3(256), 0, stream>>>(x, out);
}